// Round 5
// baseline (772.900 us; speedup 1.0000x reference)
//
#include <hip/hip_runtime.h>

// LQR2: NS=32, NC=16, T=64, NB=512, NSC=48
// out: x[512][64][32] | u[512][64][16] | cost[512]
// ws:  K^T fp32 [512][64][32][16]  then k fp32 [512][64][16]
//
// R5: ONE WAVE PER BATCH ELEMENT (512 blocks x 64 threads), ZERO barriers.
// All phases run wave-synchronously; in-wave LDS ordering (lgkmcnt) replaces
// __syncthreads. Solve = readlane LU + right-looking back-sub. Cost computed
// analytically during backward (dx0=0 identity). Forward = same wave.

#define NSd 32
#define NCd 16
#define Td 64
#define NBd 512

typedef __bf16 bf16x8 __attribute__((ext_vector_type(8)));
typedef __bf16 bf16x4 __attribute__((ext_vector_type(4)));
typedef float f32x4 __attribute__((ext_vector_type(4)));

#define MFMA16(a, b, c) __builtin_amdgcn_mfma_f32_16x16x32_bf16(a, b, c, 0, 0, 0)

#define XOFF ((size_t)0)
#define UOFF ((size_t)NBd * Td * NSd)
#define COFF (UOFF + (size_t)NBd * Td * NCd)

__device__ __forceinline__ float rdl(float v, int l) {
  return __uint_as_float(__builtin_amdgcn_readlane(__float_as_uint(v), l));
}

__global__ __launch_bounds__(64) void lqr_kernel(
    const float* __restrict__ x_init, const float* __restrict__ Qg,
    const float* __restrict__ pg, const float* __restrict__ Ag,
    const float* __restrict__ Bg, float* __restrict__ out,
    float* __restrict__ wsK, float* __restrict__ wskv) {
  const int b = blockIdx.x;
  const int lane = threadIdx.x;
  const int fn = lane & 15;
  const int quad = lane >> 4;
  const int k0 = quad * 8;

  // ---------------- LDS (~59 KB; 2 blocks/CU, grid-limited anyway) --------
  __shared__ __attribute__((aligned(16))) float sQ[2304];
  __shared__ float scx[Td][NSd];
  __shared__ float sFf[NSd][48];
  __shared__ __attribute__((aligned(16))) __bf16 FTh[48][32], FTl[48][32];
  __shared__ __attribute__((aligned(16))) __bf16 Vh[32][32], Vl[32][32];
  __shared__ __attribute__((aligned(16))) __bf16 WTh[48][32], WTl[48][32];
  __shared__ __attribute__((aligned(16))) __bf16 Xh[32][32], Xl[32][32];
  __shared__ __attribute__((aligned(16))) __bf16 KTh[32][32], KTl[32][32];
  __shared__ float sQuu[16][17];
  __shared__ float sqt[48];
  __shared__ float svv[32];
  __shared__ __attribute__((aligned(16))) float fK[2][16 * 36];  // fwd K^T
  __shared__ float fk[2][16], fd[32], fx[32], fu[16];

  // ---------------- setup (single wave; in-wave ordering) ----------------
#pragma unroll
  for (int ii = 0; ii < 24; ++ii) {
    int idx = lane + 64 * ii;
    int i = idx / 48, j = idx - i * 48;
    sFf[i][j] = (j < 32) ? Ag[i * 32 + j] : Bg[i * 16 + (j - 32)];
  }
#pragma unroll
  for (int ii = 0; ii < 24; ++ii) {
    int idx = lane + 64 * ii;
    int a = idx >> 5, k = idx & 31;
    float f = (a < 32) ? Ag[k * 32 + a] : Bg[k * 16 + (a - 32)];
    __bf16 h = (__bf16)f;
    FTh[a][k] = h;
    FTl[a][k] = (__bf16)(f - (float)h);
  }
#pragma unroll
  for (int ii = 0; ii < 16; ++ii) {
    int idx = lane + 64 * ii;
    int r = idx >> 5, c = idx & 31;
    __bf16 z = (__bf16)0.f;
    Vh[r][c] = z; Vl[r][c] = z;
    Xh[r][c] = z; Xl[r][c] = z;
    KTh[r][c] = z; KTl[r][c] = z;
  }
  if (lane < 32) {
    scx[0][lane] = x_init[b * 32 + lane];
    svv[lane] = 0.f;
  }
  {  // stage Q[b,63]
    const float4* src = (const float4*)(Qg + ((size_t)b * Td + 63) * 2304);
    float4* dst = (float4*)sQ;
#pragma unroll
    for (int i = 0; i < 9; ++i) dst[lane + 64 * i] = src[lane + 64 * i];
  }
  float ppf = 0.f;
  if (lane < 48) ppf = pg[((size_t)b * Td + 63) * 48 + lane];

  // cx rollout (wave-synchronous)
  for (int t2 = 0; t2 < Td - 1; ++t2) {
    if (lane < 32) {
      float acc = 0.f;
#pragma unroll
      for (int j = 0; j < 32; j += 4) {
        float4 a4 = *(const float4*)&sFf[lane][j];
        acc += a4.x * scx[t2][j] + a4.y * scx[t2][j + 1] +
               a4.z * scx[t2][j + 2] + a4.w * scx[t2][j + 3];
      }
      scx[t2 + 1][lane] = acc;
    }
  }

  float cAcc = 0.f;  // lanes<32: sum_t (0.5 cx'Q cx + p.cx)
  float dAcc = 0.f;  // lane 32:  sum_t 0.5 qu.kt

  // ---------------- backward Riccati: zero barriers ----------------
  for (int t = Td - 1; t >= 0; --t) {
    float4 pf[9];
    float ppfn;
    if (t > 0) {  // prefetch Q[t-1], p[t-1] into regs
      const float4* src = (const float4*)(Qg + ((size_t)b * Td + (t - 1)) * 2304);
#pragma unroll
      for (int i = 0; i < 9; ++i) pf[i] = src[lane + 64 * i];
      if (lane < 48) ppfn = pg[((size_t)b * Td + t - 1) * 48 + lane];
    }
    // Phase A: qt = p + Q*cx + F'v ; cost const term
    if (lane < 48) {
      float acc1 = ppf;
#pragma unroll
      for (int k = 0; k < 32; ++k) acc1 += sQ[k * 48 + lane] * scx[t][k];
      float acc = acc1;
#pragma unroll
      for (int k = 0; k < 32; ++k) acc += svv[k] * sFf[k][lane];
      sqt[lane] = acc;
      if (lane < 32) cAcc += 0.5f * scx[t][lane] * (acc1 + ppf);
    }
    if (t > 0 && lane < 48) ppf = ppfn;

    // Phase B: WT = F^T V  (6 tiles, 18 MFMA)
#pragma unroll
    for (int I = 0; I < 3; ++I) {
      bf16x8 aH = *(const bf16x8*)&FTh[16 * I + fn][k0];
      bf16x8 aL = *(const bf16x8*)&FTl[16 * I + fn][k0];
#pragma unroll
      for (int J = 0; J < 2; ++J) {
        bf16x8 bH = *(const bf16x8*)&Vh[16 * J + fn][k0];
        bf16x8 bL = *(const bf16x8*)&Vl[16 * J + fn][k0];
        f32x4 acc = {0.f, 0.f, 0.f, 0.f};
        acc = MFMA16(aL, bH, acc);
        acc = MFMA16(aH, bL, acc);
        acc = MFMA16(aH, bH, acc);
#pragma unroll
        for (int r = 0; r < 4; ++r) {
          float v = acc[r];
          __bf16 h = (__bf16)v;
          WTh[16 * I + 4 * quad + r][16 * J + fn] = h;
          WTl[16 * I + 4 * quad + r][16 * J + fn] = (__bf16)(v - (float)h);
        }
      }
    }

    // Phase C: Qt = Q + WT@F  (6 tiles). Qxx -> regs, Qxu -> X, Quu -> LDS.
    bf16x8 wt0H = *(const bf16x8*)&WTh[fn][k0];
    bf16x8 wt0L = *(const bf16x8*)&WTl[fn][k0];
    bf16x8 wt1H = *(const bf16x8*)&WTh[16 + fn][k0];
    bf16x8 wt1L = *(const bf16x8*)&WTl[16 + fn][k0];
    bf16x8 wt2H = *(const bf16x8*)&WTh[32 + fn][k0];
    bf16x8 wt2L = *(const bf16x8*)&WTl[32 + fn][k0];
    bf16x8 ft0H = *(const bf16x8*)&FTh[fn][k0];
    bf16x8 ft0L = *(const bf16x8*)&FTl[fn][k0];
    bf16x8 ft1H = *(const bf16x8*)&FTh[16 + fn][k0];
    bf16x8 ft1L = *(const bf16x8*)&FTl[16 + fn][k0];
    bf16x8 ft2H = *(const bf16x8*)&FTh[32 + fn][k0];
    bf16x8 ft2L = *(const bf16x8*)&FTl[32 + fn][k0];
    f32x4 accQ0, accQ1, accQ2;
#pragma unroll
    for (int r = 0; r < 4; ++r) {
      accQ0[r] = sQ[(4 * quad + r) * 48 + fn];
      accQ1[r] = sQ[(16 + 4 * quad + r) * 48 + 16 + fn];
      accQ2[r] = sQ[(4 * quad + r) * 48 + 16 + fn];
    }
    accQ0 = MFMA16(wt0L, ft0H, accQ0);
    accQ0 = MFMA16(wt0H, ft0L, accQ0);
    accQ0 = MFMA16(wt0H, ft0H, accQ0);
    accQ1 = MFMA16(wt1L, ft1H, accQ1);
    accQ1 = MFMA16(wt1H, ft1L, accQ1);
    accQ1 = MFMA16(wt1H, ft1H, accQ1);
    accQ2 = MFMA16(wt0L, ft1H, accQ2);
    accQ2 = MFMA16(wt0H, ft1L, accQ2);
    accQ2 = MFMA16(wt0H, ft1H, accQ2);
    {  // Qxu tile (0,2) -> X rows 0-15
      f32x4 acc;
#pragma unroll
      for (int r = 0; r < 4; ++r) acc[r] = sQ[(4 * quad + r) * 48 + 32 + fn];
      acc = MFMA16(wt0L, ft2H, acc);
      acc = MFMA16(wt0H, ft2L, acc);
      acc = MFMA16(wt0H, ft2H, acc);
#pragma unroll
      for (int r = 0; r < 4; ++r) {
        float v = acc[r];
        __bf16 h = (__bf16)v;
        Xh[4 * quad + r][fn] = h;
        Xl[4 * quad + r][fn] = (__bf16)(v - (float)h);
      }
    }
    {  // Qxu tile (1,2) -> X rows 16-31
      f32x4 acc;
#pragma unroll
      for (int r = 0; r < 4; ++r) acc[r] = sQ[(16 + 4 * quad + r) * 48 + 32 + fn];
      acc = MFMA16(wt1L, ft2H, acc);
      acc = MFMA16(wt1H, ft2L, acc);
      acc = MFMA16(wt1H, ft2H, acc);
#pragma unroll
      for (int r = 0; r < 4; ++r) {
        float v = acc[r];
        __bf16 h = (__bf16)v;
        Xh[16 + 4 * quad + r][fn] = h;
        Xl[16 + 4 * quad + r][fn] = (__bf16)(v - (float)h);
      }
    }
    {  // Quu tile (2,2) -> LDS fp32
      f32x4 acc;
#pragma unroll
      for (int r = 0; r < 4; ++r) acc[r] = sQ[(32 + 4 * quad + r) * 48 + 32 + fn];
      acc = MFMA16(wt2L, ft2H, acc);
      acc = MFMA16(wt2H, ft2L, acc);
      acc = MFMA16(wt2H, ft2H, acc);
#pragma unroll
      for (int r = 0; r < 4; ++r) sQuu[4 * quad + r][fn] = acc[r];
    }
    // commit Q prefetch (all sQ reads for this step are done)
    if (t > 0) {
      float4* dst = (float4*)sQ;
#pragma unroll
      for (int i = 0; i < 9; ++i) dst[lane + 64 * i] = pf[i];
    }

    // Phase D: solve Quu * X = [Qux | qu]  (readlane LU, right-looking b-sub)
    float rhs[16];
    if (lane < 32) {
      bf16x8 xh0 = *(const bf16x8*)&Xh[lane][0];
      bf16x8 xh1 = *(const bf16x8*)&Xh[lane][8];
      bf16x8 xl0 = *(const bf16x8*)&Xl[lane][0];
      bf16x8 xl1 = *(const bf16x8*)&Xl[lane][8];
#pragma unroll
      for (int i = 0; i < 8; ++i) {
        rhs[i] = (float)xh0[i] + (float)xl0[i];
        rhs[8 + i] = (float)xh1[i] + (float)xl1[i];
      }
    } else {
#pragma unroll
      for (int i = 0; i < 16; ++i) rhs[i] = sqt[32 + i];
    }
    float quu[16];
#pragma unroll
    for (int i = 0; i < 16; ++i) quu[i] = sQuu[i][fn];
#pragma unroll
    for (int r = 0; r < 15; ++r) {
      float inv = __builtin_amdgcn_rcpf(rdl(quu[r], r));
#pragma unroll
      for (int i = r + 1; i < 16; ++i) {
        float m = rdl(quu[i], r) * inv;
        rhs[i] -= m * rhs[r];
        quu[i] -= m * quu[r];
      }
    }
    float xx[16];
#pragma unroll
    for (int r = 15; r >= 0; --r) {
      float xr = rhs[r] * __builtin_amdgcn_rcpf(rdl(quu[r], r));
      xx[r] = xr;
#pragma unroll
      for (int i = 0; i < r; ++i) rhs[i] -= rdl(quu[i], r) * xr;
    }
    if (lane < 32) {  // Kt^T bf16 -> LDS; fp32 K -> ws
      bf16x8 h0, l0, h1, l1;
#pragma unroll
      for (int u = 0; u < 8; ++u) {
        float kv = -xx[u];
        __bf16 hh = (__bf16)kv;
        h0[u] = hh; l0[u] = (__bf16)(kv - (float)hh);
        float kv2 = -xx[8 + u];
        __bf16 hh2 = (__bf16)kv2;
        h1[u] = hh2; l1[u] = (__bf16)(kv2 - (float)hh2);
      }
      *(bf16x8*)&KTh[lane][0] = h0;
      *(bf16x8*)&KTh[lane][8] = h1;
      *(bf16x8*)&KTl[lane][0] = l0;
      *(bf16x8*)&KTl[lane][8] = l1;
      float4* dst = (float4*)(wsK + (((size_t)b * Td + t) * 32 + lane) * 16);
      float4 v0 = {-xx[0], -xx[1], -xx[2], -xx[3]};
      float4 v1 = {-xx[4], -xx[5], -xx[6], -xx[7]};
      float4 v2 = {-xx[8], -xx[9], -xx[10], -xx[11]};
      float4 v3 = {-xx[12], -xx[13], -xx[14], -xx[15]};
      dst[0] = v0; dst[1] = v1; dst[2] = v2; dst[3] = v3;
    } else if (lane == 32) {  // kt -> ws; cost term
      float4* dst = (float4*)(wskv + ((size_t)b * Td + t) * 16);
      float4 v0 = {-xx[0], -xx[1], -xx[2], -xx[3]};
      float4 v1 = {-xx[4], -xx[5], -xx[6], -xx[7]};
      float4 v2 = {-xx[8], -xx[9], -xx[10], -xx[11]};
      float4 v3 = {-xx[12], -xx[13], -xx[14], -xx[15]};
      dst[0] = v0; dst[1] = v1; dst[2] = v2; dst[3] = v3;
      float s = 0.f;
#pragma unroll
      for (int i = 0; i < 16; ++i) s += sqt[32 + i] * xx[i];
      dAcc -= 0.5f * s;
    }

    // Phase E: Vn = Qxx + Qxu@Kt (3 tiles + mirror); vn
    {
      bf16x8 x0H = *(const bf16x8*)&Xh[fn][k0];
      bf16x8 x0L = *(const bf16x8*)&Xl[fn][k0];
      bf16x8 x1H = *(const bf16x8*)&Xh[16 + fn][k0];
      bf16x8 x1L = *(const bf16x8*)&Xl[16 + fn][k0];
      bf16x8 kt0H = *(const bf16x8*)&KTh[fn][k0];
      bf16x8 kt0L = *(const bf16x8*)&KTl[fn][k0];
      bf16x8 kt1H = *(const bf16x8*)&KTh[16 + fn][k0];
      bf16x8 kt1L = *(const bf16x8*)&KTl[16 + fn][k0];
      accQ0 = MFMA16(x0L, kt0H, accQ0);
      accQ0 = MFMA16(x0H, kt0L, accQ0);
      accQ0 = MFMA16(x0H, kt0H, accQ0);
      accQ1 = MFMA16(x1L, kt1H, accQ1);
      accQ1 = MFMA16(x1H, kt1L, accQ1);
      accQ1 = MFMA16(x1H, kt1H, accQ1);
      accQ2 = MFMA16(x0L, kt1H, accQ2);
      accQ2 = MFMA16(x0H, kt1L, accQ2);
      accQ2 = MFMA16(x0H, kt1H, accQ2);
#pragma unroll
      for (int r = 0; r < 4; ++r) {
        float v = accQ0[r];
        __bf16 h = (__bf16)v;
        Vh[4 * quad + r][fn] = h;
        Vl[4 * quad + r][fn] = (__bf16)(v - (float)h);
      }
#pragma unroll
      for (int r = 0; r < 4; ++r) {
        float v = accQ1[r];
        __bf16 h = (__bf16)v;
        Vh[16 + 4 * quad + r][16 + fn] = h;
        Vl[16 + 4 * quad + r][16 + fn] = (__bf16)(v - (float)h);
      }
      bf16x4 th, tl;
#pragma unroll
      for (int r = 0; r < 4; ++r) {
        float v = accQ2[r];
        __bf16 h = (__bf16)v;
        __bf16 l = (__bf16)(v - (float)h);
        Vh[4 * quad + r][16 + fn] = h;
        Vl[4 * quad + r][16 + fn] = l;
        th[r] = h; tl[r] = l;
      }
      *(bf16x4*)&Vh[16 + fn][4 * quad] = th;  // mirror (V symmetric)
      *(bf16x4*)&Vl[16 + fn][4 * quad] = tl;
    }
    {  // vn = qx + Qxu @ kt  (kt = -xx on lane 32)
      float acc = 0.f;
      bf16x8 xh0, xh1, xl0, xl1;
      if (lane < 32) {
        xh0 = *(const bf16x8*)&Xh[lane][0];
        xh1 = *(const bf16x8*)&Xh[lane][8];
        xl0 = *(const bf16x8*)&Xl[lane][0];
        xl1 = *(const bf16x8*)&Xl[lane][8];
        acc = sqt[lane];
      }
#pragma unroll
      for (int u = 0; u < 8; ++u) {
        float kt0 = -rdl(xx[u], 32);
        float kt1 = -rdl(xx[8 + u], 32);
        if (lane < 32) {
          acc += ((float)xh0[u] + (float)xl0[u]) * kt0;
          acc += ((float)xh1[u] + (float)xl1[u]) * kt1;
        }
      }
      if (lane < 32) svv[lane] = acc;
    }
  }

  // ---------------- cost ----------------
  {
    float rv = (lane < 32) ? cAcc : ((lane == 32) ? dAcc : 0.f);
    rv += __shfl_down(rv, 32);
    rv += __shfl_down(rv, 16);
    rv += __shfl_down(rv, 8);
    rv += __shfl_down(rv, 4);
    rv += __shfl_down(rv, 2);
    rv += __shfl_down(rv, 1);
    if (lane == 0) out[COFF + b] = rv;
  }

  // ---------------- forward rollout (same wave, barrier-free) ----------------
  {  // preload K_0, k_0 (transposed, stride 36)
    const float4* src = (const float4*)(wsK + ((size_t)b * Td) * 512);
    float4 ka = src[lane * 2], kb = src[lane * 2 + 1];
    int jj = lane >> 1, ib = (lane & 1) * 8;
    float* kt2 = fK[0];
    kt2[(ib + 0) * 36 + jj] = ka.x; kt2[(ib + 1) * 36 + jj] = ka.y;
    kt2[(ib + 2) * 36 + jj] = ka.z; kt2[(ib + 3) * 36 + jj] = ka.w;
    kt2[(ib + 4) * 36 + jj] = kb.x; kt2[(ib + 5) * 36 + jj] = kb.y;
    kt2[(ib + 6) * 36 + jj] = kb.z; kt2[(ib + 7) * 36 + jj] = kb.w;
    if (lane < 16) fk[0][lane] = wskv[(size_t)b * Td * 16 + lane];
  }
  float xr = (lane < 32) ? scx[0][lane] : 0.f;
  for (int t = 0; t < Td; ++t) {
    const int cur = t & 1, nxt = cur ^ 1;
    float4 pa, pb;
    float pk;
    if (t < Td - 1) {  // prefetch K_{t+1}
      const float4* src = (const float4*)(wsK + ((size_t)b * Td + t + 1) * 512);
      pa = src[lane * 2];
      pb = src[lane * 2 + 1];
      if (lane < 16) pk = wskv[((size_t)b * Td + t + 1) * 16 + lane];
    }
    if (lane < 32) {  // d = x - cx; stash x; emit x
      fd[lane] = xr - scx[t][lane];
      fx[lane] = xr;
      out[XOFF + ((size_t)b * Td + t) * 32 + lane] = xr;
    }
    if (lane < 16) {  // u = k + K d; emit u
      float uv = fk[cur][lane];
      const float* kr = &fK[cur][lane * 36];
#pragma unroll
      for (int j4 = 0; j4 < 8; ++j4) {
        float4 kk = *(const float4*)&kr[j4 * 4];
        float4 dd = *(const float4*)&fd[j4 * 4];
        uv += kk.x * dd.x + kk.y * dd.y + kk.z * dd.z + kk.w * dd.w;
      }
      fu[lane] = uv;
      out[UOFF + ((size_t)b * Td + t) * 16 + lane] = uv;
    }
    if (lane < 32) {  // x' = A x + B u
      float acc = 0.f;
#pragma unroll
      for (int j4 = 0; j4 < 8; ++j4) {
        float4 ff = *(const float4*)&sFf[lane][j4 * 4];
        float4 xv = *(const float4*)&fx[j4 * 4];
        acc += ff.x * xv.x + ff.y * xv.y + ff.z * xv.z + ff.w * xv.w;
      }
#pragma unroll
      for (int j4 = 0; j4 < 4; ++j4) {
        float4 ff = *(const float4*)&sFf[lane][32 + j4 * 4];
        float4 uv = *(const float4*)&fu[j4 * 4];
        acc += ff.x * uv.x + ff.y * uv.y + ff.z * uv.z + ff.w * uv.w;
      }
      xr = acc;
    }
    if (t < Td - 1) {  // commit K_{t+1}
      int jj = lane >> 1, ib = (lane & 1) * 8;
      float* kt2 = fK[nxt];
      kt2[(ib + 0) * 36 + jj] = pa.x; kt2[(ib + 1) * 36 + jj] = pa.y;
      kt2[(ib + 2) * 36 + jj] = pa.z; kt2[(ib + 3) * 36 + jj] = pa.w;
      kt2[(ib + 4) * 36 + jj] = pb.x; kt2[(ib + 5) * 36 + jj] = pb.y;
      kt2[(ib + 6) * 36 + jj] = pb.z; kt2[(ib + 7) * 36 + jj] = pb.w;
      if (lane < 16) fk[nxt][lane] = pk;
    }
  }
}

extern "C" void kernel_launch(void* const* d_in, const int* in_sizes, int n_in,
                              void* d_out, int out_size, void* d_ws, size_t ws_size,
                              hipStream_t stream) {
  const float* x_init = (const float*)d_in[0];
  const float* Qg = (const float*)d_in[1];
  const float* pg = (const float*)d_in[2];
  const float* Ag = (const float*)d_in[3];
  const float* Bg = (const float*)d_in[4];
  float* out = (float*)d_out;
  float* wsK = (float*)d_ws;
  float* wskv = wsK + (size_t)NBd * Td * NSd * NCd;
  lqr_kernel<<<NBd, 64, 0, stream>>>(x_init, Qg, pg, Ag, Bg, out, wsK, wskv);
}